// Round 6
// baseline (174.440 us; speedup 1.0000x reference)
//
#include <hip/hip_runtime.h>

#pragma clang fp contract(off)

#define H_ 192
#define W_ 192
#define HW_ (192 * 192)
#define NSC 3
#define NCAND (NSC * HW_)
#define CCH 256
#define KMAX 2048
#define NBIN 4096

// d_out layout (floats), in reference return order:
// keypoints [2048,2], descriptors [2048,256], scores [2048], det0/1/2 [192,192]
#define KP_OFF 0
#define DESC_OFF (KMAX * 2)
#define SC_OFF (DESC_OFF + KMAX * CCH)
#define DET_OFF (SC_OFF + KMAX)

typedef unsigned long long u64;
typedef unsigned int u32;

// ws layout (bytes):
//      0 : fin keys   u64[NCAND]      884736
// 884736 : cnts       u32[16]         64      [0]=nfin            (memset 0)
// 884800 : ghist      u32[NBIN]       16384                       (memset 0)
// 901248 : slotinfo   float4[KMAX]    32768   (zeroed in select_kernel)
// 934016 : surv       u64[NCAND]      884736  (bin-grouped keys)
#define CNT_OFF 884736
#define GH_OFF 884800
#define SLOT_OFF 901248
#define SURV_OFF 934016

// Order-monotone, DISTRIBUTION-AWARE bin of the key's high word (positive
// ordered-float bits). det = max of 9 iid U[0,1) -> ~99.8% of mass in
// [0.5,1): give that range 2048 fine bins (mantissa bits 22..12); coarse
// monotone map below. Monotone at boundary: coarse max 0x3EF=1007 < 2048.
__device__ __forceinline__ u32 key_bin(u32 sb) {
    if (sb >= 0xBF800000u) return NBIN - 1;                        // det>=1: safety
    if (sb >= 0xBF000000u) return 2048u + ((sb >> 12) & 0x7FFu);   // det in [0.5,1)
    return (sb >> 20) & 0x7FFu;                                    // det in (0,0.5)
}

// Exact replica of the reference per-pixel math. FP contraction OFF for this
// TU -> float ops match numpy bit-for-bit. OOB taps read as 0.0, INCLUDING in
// the max: provably identical to the -inf-padded maxpool because scores>=0
// (zeros can't beat c>0; c==0 gives det=0 either way).
__device__ __forceinline__ void newton_pixel(const float* __restrict__ sm, int i, int j,
                                             float& det, float& ki, float& kj, bool& valid) {
    float v[3][3];
#pragma unroll
    for (int a = 0; a < 3; ++a) {
#pragma unroll
        for (int b = 0; b < 3; ++b) {
            int ii = i + a - 1, jj = j + b - 1;
            bool in = (ii >= 0) && (ii < H_) && (jj >= 0) && (jj < W_);
            v[a][b] = in ? sm[ii * W_ + jj] : 0.0f;
        }
    }
    float c = v[1][1];
    float mx = v[0][0];
    mx = fmaxf(mx, v[0][1]); mx = fmaxf(mx, v[0][2]);
    mx = fmaxf(mx, v[1][0]); mx = fmaxf(mx, c);
    mx = fmaxf(mx, v[1][2]); mx = fmaxf(mx, v[2][0]);
    mx = fmaxf(mx, v[2][1]); mx = fmaxf(mx, v[2][2]);
    det = (mx == c) ? c : 0.0f;
    float di  = -0.5f * v[0][1] + 0.5f * v[2][1];
    float dj  = -0.5f * v[1][0] + 0.5f * v[1][2];
    float dii = v[0][1] - 2.0f * c + v[2][1];
    float djj = v[1][0] - 2.0f * c + v[1][2];
    float dij = 0.25f * v[0][0] - 0.25f * v[0][2] - 0.25f * v[2][0] + 0.25f * v[2][2];
    float dd = dii * djj - dij * dij;
    if (dd == 0.0f) dd = 1e-20f;
    float step_i = -(djj * di - dij * dj) / dd;
    float step_j = -(-dij * di + dii * dj) / dd;
    valid = (det != 0.0f) && (fabsf(step_i) < 0.5f) && (fabsf(step_j) < 0.5f);
    ki = valid ? ((float)i + step_i) : 0.0f;
    kj = valid ? ((float)j + step_j) : 0.0f;
    float i0 = floorf(ki), j0 = floorf(kj);
    valid = valid && (i0 >= 0.0f) && (j0 >= 0.0f) &&
            (i0 + 1.0f <= (float)(H_ - 1)) && (j0 + 1.0f <= (float)(W_ - 1));
}

__device__ __forceinline__ void decode_gid(u32 gid, int& s, int& i, int& j) {
    s = (int)(gid / HW_);
    int rem = (int)gid - s * HW_;
    i = rem / W_;
    j = rem - i * W_;
}

// Kernel 1: per-pixel NMS/Newton; det maps; append valid keys; global-atomic
// score-bin histogram (~12k valid keys over ~2k hot bins -> no contention).
__global__ __launch_bounds__(256) void cand_kernel(
    const float* __restrict__ s0, const float* __restrict__ s1, const float* __restrict__ s2,
    float* __restrict__ out, u64* __restrict__ fin, u32* __restrict__ cnts,
    u32* __restrict__ ghist) {
    __shared__ u32 lcnt, base;
    int tid = threadIdx.x;
    if (tid == 0) lcnt = 0;
    __syncthreads();
    int t = blockIdx.x * 256 + tid;
    bool valid = false;
    u64 key = 0;
    {
        int s, i, j;
        decode_gid((u32)t, s, i, j);
        const float* sm = (s == 0) ? s0 : (s == 1) ? s1 : s2;
        float det, ki, kj;
        newton_pixel(sm, i, j, det, ki, kj, valid);
        out[DET_OFF + t] = det;
        if (valid) {
            u32 sb = __float_as_uint(det) | 0x80000000u;  // det>0: ordered bits
            key = ((u64)sb << 32) | (u64)(0xFFFFFFFFu - (u32)t);  // ties: lower idx first
            atomicAdd(&ghist[key_bin(sb)], 1u);
        }
    }
    u32 lpos = 0;
    if (valid) lpos = atomicAdd(&lcnt, 1u);
    __syncthreads();
    if (tid == 0 && lcnt > 0) base = atomicAdd(&cnts[0], lcnt);
    __syncthreads();
    if (valid) fin[base + lpos] = key;
}

// Kernel 2 (ONE block, 1024 thr): fused suffix-scan + bin-scatter + exact
// rank. S[b]=#keys bin>=b in LDS; segment of bin b = [S[b+1],S[b]); key's
// global rank = S[b+1] + #{same-bin keys greater} (segments avg ~13 keys).
// Winners (<2048) recompute newton once, write slot float4 (ki,kj,det,scale).
__global__ __launch_bounds__(1024) void select_kernel(
    const u64* __restrict__ fin, const u32* __restrict__ cnts, const u32* __restrict__ ghist,
    u64* __restrict__ surv,
    const float* __restrict__ s0, const float* __restrict__ s1, const float* __restrict__ s2,
    float4* __restrict__ slot) {
    __shared__ u32 ls[NBIN + 1];
    __shared__ u32 cur[NBIN];
    __shared__ u32 lT[1024];
    __shared__ u32 sh_m;
    int t = threadIdx.x;
    // zero slot rows (padding rows -> det==0 -> output emits zeros)
    float4 z = make_float4(0.0f, 0.0f, 0.0f, 0.0f);
    for (int r = t; r < KMAX; r += 1024) slot[r] = z;
    // ---- suffix scan over 4096-bin histogram (4 bins/thread) ----
    u32 c[4];
    u32 acc = 0;
#pragma unroll
    for (int k = 3; k >= 0; --k) {
        acc += ghist[t * 4 + k];
        c[k] = acc;  // suffix within chunk
    }
    lT[t] = acc;
    __syncthreads();
    for (int off = 1; off < 1024; off <<= 1) {
        u32 v = lT[t] + ((t + off < 1024) ? lT[t + off] : 0u);
        __syncthreads();
        lT[t] = v;
        __syncthreads();
    }
    u32 add = (t < 1023) ? lT[t + 1] : 0u;
#pragma unroll
    for (int k = 0; k < 4; ++k) ls[t * 4 + k] = c[k] + add;
    if (t == 0) ls[NBIN] = 0;
    __syncthreads();
#pragma unroll
    for (int k = 0; k < 4; ++k) {
        u32 b = t * 4 + k;
        cur[b] = ls[b + 1];  // scatter cursor = segment base
        if (ls[b + 1] < KMAX && (b == 0 || ls[b] >= KMAX)) sh_m = ls[b];
    }
    __syncthreads();
    // ---- scatter qualifying keys (segment base < KMAX) into bin groups ----
    u32 n = cnts[0];
    for (u32 idx = (u32)t; idx < n; idx += 1024) {
        u64 key = fin[idx];
        u32 b = key_bin((u32)(key >> 32));
        if (ls[b + 1] < KMAX) {
            u32 pos = atomicAdd(&cur[b], 1u);
            surv[pos] = key;
        }
    }
    __syncthreads();
    // ---- exact rank within segment; winners fill slot ----
    u32 m = sh_m;
    for (u32 p = (u32)t; p < m; p += 1024) {
        u64 key = surv[p];
        u32 b = key_bin((u32)(key >> 32));
        u32 lo = ls[b + 1], hi = ls[b];
        u32 rank = lo;
        for (u32 q = lo; q < hi; ++q) rank += (surv[q] > key) ? 1u : 0u;
        if (rank < KMAX) {
            u32 gid = 0xFFFFFFFFu - (u32)(key & 0xFFFFFFFFull);
            int s, i, j;
            decode_gid(gid, s, i, j);
            const float* sm = (s == 0) ? s0 : (s == 1) ? s1 : s2;
            float det, ki, kj;
            bool valid;
            newton_pixel(sm, i, j, det, ki, kj, valid);
            slot[rank] = make_float4(ki, kj, det, (float)s);
        }
    }
}

// Kernel 3: one block (256 threads = 256 channels) per output slot. Pure
// bilinear gather + L2-normalize; padding rows (det==0) -> zeros.
__global__ __launch_bounds__(256) void output_kernel(
    const float4* __restrict__ slot,
    const float* __restrict__ f0, const float* __restrict__ f1, const float* __restrict__ f2,
    float* __restrict__ out) {
    __shared__ float red[4];
    int r = blockIdx.x;
    int tid = threadIdx.x;
    float4 info = slot[r];
    if (info.z == 0.0f) {  // padding
        out[DESC_OFF + r * CCH + tid] = 0.0f;
        if (tid == 0) {
            out[SC_OFF + r] = 0.0f;
            out[KP_OFF + r * 2 + 0] = 0.0f;
            out[KP_OFF + r * 2 + 1] = 0.0f;
        }
        return;
    }
    float ki = info.x, kj = info.y;
    int s = (int)info.w;
    const float* feat = (s == 0) ? f0 : (s == 1) ? f1 : f2;
    int i0 = (int)floorf(ki), j0 = (int)floorf(kj);
    float wi = ki - (float)i0;
    float wj = kj - (float)j0;
    const float* p = feat + (size_t)tid * HW_ + i0 * W_ + j0;
    float f00 = p[0], f01 = p[1], f10 = p[W_], f11 = p[W_ + 1];
    float d = f00 * (1.0f - wi) * (1.0f - wj) + f01 * (1.0f - wi) * wj +
              f10 * wi * (1.0f - wj) + f11 * wi * wj;
    float sq = d * d;
#pragma unroll
    for (int o = 32; o > 0; o >>= 1) sq += __shfl_down(sq, o, 64);
    if ((tid & 63) == 0) red[tid >> 6] = sq;
    __syncthreads();
    float norm = fmaxf(sqrtf(red[0] + red[1] + red[2] + red[3]), 1e-12f);
    out[DESC_OFF + r * CCH + tid] = d / norm;
    if (tid == 0) {
        out[SC_OFF + r] = info.z;
        float x = kj, y = ki;
#pragma unroll
        for (int u = 0; u < 4; ++u) { x = x * 2.0f + 0.5f; y = y * 2.0f + 0.5f; }
        out[KP_OFF + r * 2 + 0] = x;  // (x=col, y=row)
        out[KP_OFF + r * 2 + 1] = y;
    }
}

extern "C" void kernel_launch(void* const* d_in, const int* in_sizes, int n_in,
                              void* d_out, int out_size, void* d_ws, size_t ws_size,
                              hipStream_t stream) {
    const float* f0 = (const float*)d_in[0];
    const float* f1 = (const float*)d_in[1];
    const float* f2 = (const float*)d_in[2];
    const float* s0 = (const float*)d_in[3];
    const float* s1 = (const float*)d_in[4];
    const float* s2 = (const float*)d_in[5];
    float* out = (float*)d_out;

    char* ws = (char*)d_ws;
    u64* fin = (u64*)ws;
    u32* cnts = (u32*)(ws + CNT_OFF);
    u32* ghist = (u32*)(ws + GH_OFF);
    float4* slot = (float4*)(ws + SLOT_OFF);
    u64* surv = (u64*)(ws + SURV_OFF);

    // zero cnts + ghist (contiguous) in one memset; slot zeroed in-kernel
    hipMemsetAsync(ws + CNT_OFF, 0, 64 + NBIN * 4, stream);
    cand_kernel<<<NCAND / 256, 256, 0, stream>>>(s0, s1, s2, out, fin, cnts, ghist);
    select_kernel<<<1, 1024, 0, stream>>>(fin, cnts, ghist, surv, s0, s1, s2, slot);
    output_kernel<<<KMAX, 256, 0, stream>>>(slot, f0, f1, f2, out);
}

// Round 7
// 163.343 us; speedup vs baseline: 1.0679x; 1.0679x over previous
//
#include <hip/hip_runtime.h>

#pragma clang fp contract(off)

#define H_ 192
#define W_ 192
#define HW_ (192 * 192)
#define NSC 3
#define NCAND (NSC * HW_)
#define CCH 256
#define KMAX 2048
#define NBIN 4096

// d_out layout (floats), in reference return order:
// keypoints [2048,2], descriptors [2048,256], scores [2048], det0/1/2 [192,192]
#define KP_OFF 0
#define DESC_OFF (KMAX * 2)
#define SC_OFF (DESC_OFF + KMAX * CCH)
#define DET_OFF (SC_OFF + KMAX)

typedef unsigned long long u64;
typedef unsigned int u32;

// ws layout (bytes):
//      0 : fin keys   u64[NCAND]      884736
// 884736 : cnts       u32[16]         64      [0]=nfin [2]=m(scattered)
// 884800 : slotinfo   float4[KMAX]    32768   (memset 0: det==0 -> padding row)
// 917568 : ghist      u32[NBIN]       16384   (memset 0)
// 933952 : SARR       u32[NBIN+1]     16448   (padded; written by scan)
// 950400 : cursor     u32[NBIN]       16384   (written by scan)
// 966784 : surv       u64[NCAND]      884736  (bin-grouped keys)
#define CNT_OFF 884736
#define SLOT_OFF 884800
#define GH_OFF 917568
#define SARR_OFF 933952
#define CUR_OFF 950400
#define SURV_OFF 966784

// Order-monotone, DISTRIBUTION-AWARE bin of the key's high word (positive
// ordered-float bits). det = max of 9 iid U[0,1) -> ~99.8% of mass in
// [0.5,1): give that range 2048 fine bins (mantissa bits 22..12); coarse
// monotone map below. Monotone at boundary: coarse max 0x3EF=1007 < 2048.
__device__ __forceinline__ u32 key_bin(u32 sb) {
    if (sb >= 0xBF800000u) return NBIN - 1;                        // det>=1: safety
    if (sb >= 0xBF000000u) return 2048u + ((sb >> 12) & 0x7FFu);   // det in [0.5,1)
    return (sb >> 20) & 0x7FFu;                                    // det in (0,0.5)
}

// Exact replica of the reference per-pixel math. FP contraction OFF for this
// TU -> float ops match numpy bit-for-bit. OOB taps read as 0.0, INCLUDING in
// the max: provably identical to the -inf-padded maxpool because scores>=0
// (zeros can't beat c>0; c==0 gives det=0 either way). Branchless.
__device__ __forceinline__ void newton_pixel(const float* __restrict__ sm, int i, int j,
                                             float& det, float& ki, float& kj, bool& valid) {
    float v[3][3];
#pragma unroll
    for (int a = 0; a < 3; ++a) {
#pragma unroll
        for (int b = 0; b < 3; ++b) {
            int ii = i + a - 1, jj = j + b - 1;
            bool in = (ii >= 0) && (ii < H_) && (jj >= 0) && (jj < W_);
            v[a][b] = in ? sm[ii * W_ + jj] : 0.0f;
        }
    }
    float c = v[1][1];
    float mx = v[0][0];
    mx = fmaxf(mx, v[0][1]); mx = fmaxf(mx, v[0][2]);
    mx = fmaxf(mx, v[1][0]); mx = fmaxf(mx, c);
    mx = fmaxf(mx, v[1][2]); mx = fmaxf(mx, v[2][0]);
    mx = fmaxf(mx, v[2][1]); mx = fmaxf(mx, v[2][2]);
    det = (mx == c) ? c : 0.0f;
    float di  = -0.5f * v[0][1] + 0.5f * v[2][1];
    float dj  = -0.5f * v[1][0] + 0.5f * v[1][2];
    float dii = v[0][1] - 2.0f * c + v[2][1];
    float djj = v[1][0] - 2.0f * c + v[1][2];
    float dij = 0.25f * v[0][0] - 0.25f * v[0][2] - 0.25f * v[2][0] + 0.25f * v[2][2];
    float dd = dii * djj - dij * dij;
    if (dd == 0.0f) dd = 1e-20f;
    float step_i = -(djj * di - dij * dj) / dd;
    float step_j = -(-dij * di + dii * dj) / dd;
    valid = (det != 0.0f) && (fabsf(step_i) < 0.5f) && (fabsf(step_j) < 0.5f);
    ki = valid ? ((float)i + step_i) : 0.0f;
    kj = valid ? ((float)j + step_j) : 0.0f;
    float i0 = floorf(ki), j0 = floorf(kj);
    valid = valid && (i0 >= 0.0f) && (j0 >= 0.0f) &&
            (i0 + 1.0f <= (float)(H_ - 1)) && (j0 + 1.0f <= (float)(W_ - 1));
}

__device__ __forceinline__ void decode_gid(u32 gid, int& s, int& i, int& j) {
    s = (int)(gid / HW_);
    int rem = (int)gid - s * HW_;
    i = rem / W_;
    j = rem - i * W_;
}

// Kernel 1: per-pixel NMS/Newton; det maps; append valid keys; global-atomic
// score-bin histogram (~12k valid keys over ~2k hot bins -> no contention).
__global__ __launch_bounds__(256) void cand_kernel(
    const float* __restrict__ s0, const float* __restrict__ s1, const float* __restrict__ s2,
    float* __restrict__ out, u64* __restrict__ fin, u32* __restrict__ cnts,
    u32* __restrict__ ghist) {
    __shared__ u32 lcnt, base;
    int tid = threadIdx.x;
    if (tid == 0) lcnt = 0;
    __syncthreads();
    int t = blockIdx.x * 256 + tid;
    bool valid = false;
    u64 key = 0;
    {
        int s, i, j;
        decode_gid((u32)t, s, i, j);
        const float* sm = (s == 0) ? s0 : (s == 1) ? s1 : s2;
        float det, ki, kj;
        newton_pixel(sm, i, j, det, ki, kj, valid);
        out[DET_OFF + t] = det;
        if (valid) {
            u32 sb = __float_as_uint(det) | 0x80000000u;  // det>0: ordered bits
            key = ((u64)sb << 32) | (u64)(0xFFFFFFFFu - (u32)t);  // ties: lower idx first
            atomicAdd(&ghist[key_bin(sb)], 1u);
        }
    }
    u32 lpos = 0;
    if (valid) lpos = atomicAdd(&lcnt, 1u);
    __syncthreads();
    if (tid == 0 && lcnt > 0) base = atomicAdd(&cnts[0], lcnt);
    __syncthreads();
    if (valid) fin[base + lpos] = key;
}

// Kernel 2 (1 block, 256 thr): inclusive suffix scan S[b]=#keys bin>=b over the
// 4096-bin histogram; emit SARR[0..4096], per-bin scatter cursors (=S[b+1]),
// and m = S[b0] where b0 = min{b : S[b+1] < KMAX} (keys that can rank <2048).
__global__ __launch_bounds__(256) void scan_kernel(
    const u32* __restrict__ ghist, u32* __restrict__ sarr, u32* __restrict__ cursor,
    u32* __restrict__ cnts) {
    __shared__ u32 ls[NBIN + 1];
    __shared__ u32 lT[256];
    int t = threadIdx.x;
    u32 chunk[16];
    u32 acc = 0;
#pragma unroll
    for (int k = 15; k >= 0; --k) {
        acc += ghist[t * 16 + k];
        chunk[k] = acc;  // suffix within chunk
    }
    lT[t] = acc;
    __syncthreads();
    // inclusive suffix scan of 256 chunk totals
    for (int off = 1; off < 256; off <<= 1) {
        u32 v = lT[t] + ((t + off < 256) ? lT[t + off] : 0u);
        __syncthreads();
        lT[t] = v;
        __syncthreads();
    }
    u32 add = (t < 255) ? lT[t + 1] : 0u;  // exclusive suffix of later chunks
#pragma unroll
    for (int k = 0; k < 16; ++k) ls[t * 16 + k] = chunk[k] + add;
    if (t == 0) ls[NBIN] = 0;
    __syncthreads();
#pragma unroll
    for (int k = 0; k < 16; ++k) {
        u32 b = t * 16 + k;
        sarr[b] = ls[b];
        cursor[b] = ls[b + 1];
        if (ls[b + 1] < KMAX && (b == 0 || ls[b] >= KMAX)) cnts[2] = ls[b];  // m
    }
    if (t == 0) sarr[NBIN] = 0;
}

// Kernel 3: scatter keys that can make top-2048 (bin segment base < KMAX) into
// bin-grouped order: segment of bin b = [S[b+1], S[b]).
__global__ __launch_bounds__(256) void scatter_kernel(
    const u64* __restrict__ fin, const u32* __restrict__ sarr, u32* __restrict__ cursor,
    u32* __restrict__ cnts, u64* __restrict__ surv) {
    u32 n = cnts[0];
    for (u32 idx = blockIdx.x * 256 + threadIdx.x; idx < n; idx += 64 * 256) {
        u64 key = fin[idx];
        u32 b = key_bin((u32)(key >> 32));
        if (sarr[b + 1] < KMAX) {
            u32 pos = atomicAdd(&cursor[b], 1u);
            surv[pos] = key;
        }
    }
}

// Kernel 4: exact rank = segment base + #{same-bin keys greater} (segments
// ~13 keys avg). Winners (<2048) compute their newton state once and write the
// per-slot float4 (ki, kj, det, scale) consumed by the gather kernel.
__global__ __launch_bounds__(256) void rank_kernel(
    const u64* __restrict__ surv, const u32* __restrict__ sarr, const u32* __restrict__ cnts,
    const float* __restrict__ s0, const float* __restrict__ s1, const float* __restrict__ s2,
    float4* __restrict__ slot) {
    u32 m = cnts[2];
    for (u32 p = blockIdx.x * 256 + threadIdx.x; p < m; p += 32 * 256) {
        u64 key = surv[p];
        u32 b = key_bin((u32)(key >> 32));
        u32 lo = sarr[b + 1], hi = sarr[b];
        u32 rank = lo;
        for (u32 q = lo; q < hi; ++q) rank += (surv[q] > key) ? 1u : 0u;
        if (rank < KMAX) {
            u32 gid = 0xFFFFFFFFu - (u32)(key & 0xFFFFFFFFull);
            int s, i, j;
            decode_gid(gid, s, i, j);
            const float* sm = (s == 0) ? s0 : (s == 1) ? s1 : s2;
            float det, ki, kj;
            bool valid;
            newton_pixel(sm, i, j, det, ki, kj, valid);
            slot[rank] = make_float4(ki, kj, det, (float)s);
        }
    }
}

// Kernel 5: one block (256 threads = 256 channels) per output slot. Pure
// bilinear gather + L2-normalize; padding rows (det==0 from memset) -> zeros.
__global__ __launch_bounds__(256) void output_kernel(
    const float4* __restrict__ slot,
    const float* __restrict__ f0, const float* __restrict__ f1, const float* __restrict__ f2,
    float* __restrict__ out) {
    __shared__ float red[4];
    int r = blockIdx.x;
    int tid = threadIdx.x;
    float4 info = slot[r];
    if (info.z == 0.0f) {  // padding
        out[DESC_OFF + r * CCH + tid] = 0.0f;
        if (tid == 0) {
            out[SC_OFF + r] = 0.0f;
            out[KP_OFF + r * 2 + 0] = 0.0f;
            out[KP_OFF + r * 2 + 1] = 0.0f;
        }
        return;
    }
    float ki = info.x, kj = info.y;
    int s = (int)info.w;
    const float* feat = (s == 0) ? f0 : (s == 1) ? f1 : f2;
    int i0 = (int)floorf(ki), j0 = (int)floorf(kj);
    float wi = ki - (float)i0;
    float wj = kj - (float)j0;
    const float* p = feat + (size_t)tid * HW_ + i0 * W_ + j0;
    float f00 = p[0], f01 = p[1], f10 = p[W_], f11 = p[W_ + 1];
    float d = f00 * (1.0f - wi) * (1.0f - wj) + f01 * (1.0f - wi) * wj +
              f10 * wi * (1.0f - wj) + f11 * wi * wj;
    // wave shuffle reduce of d*d, then combine 4 wave partials via LDS
    float sq = d * d;
#pragma unroll
    for (int o = 32; o > 0; o >>= 1) sq += __shfl_down(sq, o, 64);
    if ((tid & 63) == 0) red[tid >> 6] = sq;
    __syncthreads();
    float norm = fmaxf(sqrtf(red[0] + red[1] + red[2] + red[3]), 1e-12f);
    out[DESC_OFF + r * CCH + tid] = d / norm;
    if (tid == 0) {
        out[SC_OFF + r] = info.z;
        float x = kj, y = ki;
#pragma unroll
        for (int u = 0; u < 4; ++u) { x = x * 2.0f + 0.5f; y = y * 2.0f + 0.5f; }
        out[KP_OFF + r * 2 + 0] = x;  // (x=col, y=row)
        out[KP_OFF + r * 2 + 1] = y;
    }
}

extern "C" void kernel_launch(void* const* d_in, const int* in_sizes, int n_in,
                              void* d_out, int out_size, void* d_ws, size_t ws_size,
                              hipStream_t stream) {
    const float* f0 = (const float*)d_in[0];
    const float* f1 = (const float*)d_in[1];
    const float* f2 = (const float*)d_in[2];
    const float* s0 = (const float*)d_in[3];
    const float* s1 = (const float*)d_in[4];
    const float* s2 = (const float*)d_in[5];
    float* out = (float*)d_out;

    char* ws = (char*)d_ws;
    u64* fin = (u64*)ws;
    u32* cnts = (u32*)(ws + CNT_OFF);
    float4* slot = (float4*)(ws + SLOT_OFF);
    u32* ghist = (u32*)(ws + GH_OFF);
    u32* sarr = (u32*)(ws + SARR_OFF);
    u32* cursor = (u32*)(ws + CUR_OFF);
    u64* surv = (u64*)(ws + SURV_OFF);

    // zero cnts + slotinfo + ghist in one contiguous memset
    hipMemsetAsync(ws + CNT_OFF, 0, 64 + KMAX * 16 + NBIN * 4, stream);
    cand_kernel<<<NCAND / 256, 256, 0, stream>>>(s0, s1, s2, out, fin, cnts, ghist);
    scan_kernel<<<1, 256, 0, stream>>>(ghist, sarr, cursor, cnts);
    scatter_kernel<<<64, 256, 0, stream>>>(fin, sarr, cursor, cnts, surv);
    rank_kernel<<<32, 256, 0, stream>>>(surv, sarr, cnts, s0, s1, s2, slot);
    output_kernel<<<KMAX, 256, 0, stream>>>(slot, f0, f1, f2, out);
}